// Round 15
// baseline (2708.730 us; speedup 1.0000x reference)
//
#include <hip/hip_runtime.h>
#include <math.h>

#define DEVFN __device__ __forceinline__

namespace {

constexpr int NW = 320, NH = 320, NHW = NW * NH, NB = 4;
constexpr int NC2 = 2 * NHW;          // floats per complex image
constexpr int GRID = NB * NH;         // 1280 blocks (one line per block)
constexpr int NTHR = 320;             // one point per thread
constexpr float THRESHc = 0.01f;      // LAMBDA_TV / RHO

struct C2 { float x, y; };
DEVFN C2 cmul(C2 a, C2 b) { return C2{a.x * b.x - a.y * b.y, a.x * b.y + a.y * b.x}; }

template <int SIGN>
DEVFN C2 TW(const float2* tw, int m) {
  float2 t = tw[m];
  return C2{t.x, (SIGN < 0) ? t.y : -t.y};
}

// XCD-chunked swizzle (ALL FFT kernels): adjacent lines -> same XCD L2.
DEVFN int swzcol(int bid) { return (bid & 7) * (GRID / 8) + (bid >> 3); }

// thread t computes FFT output element oidx(t)
DEVFN int oidx(int t) { return 5 * (t & 63) + (t >> 6); }

// compiler fence for wave-synchronous LDS (wave64 lockstep; LDS in-order per wave)
DEVFN void wavebar() {
  __builtin_amdgcn_wave_barrier();
  asm volatile("" ::: "memory");
}

// done_before(it) = OR_{j<=it-1} stop_j   (entries beyond first-done are garbage
// but only OR into an already-true predicate -- harmless; done is monotone)
DEVFN bool doneBefore(const double* __restrict__ hp, const double* __restrict__ hd, int it) {
  bool done = false;
  for (int j = 0; j <= it - 1; j++) {
    float pr = sqrtf((float)hp[j]), dr = sqrtf((float)hd[j]);
    done |= (pr < 1e-4f && dr < 1e-4f);
  }
  return done;
}

// parity of the last-committed u/v buffer at iter `it`: min(it, first-done-iter) & 1.
// Commit(j) wrote buf[(j+1)&1]; last commit among j<it is j = min(it, d) - 1.
DEVFN int uvParity(const double* __restrict__ hp, const double* __restrict__ hd, int it) {
  bool done = false;
  int d = it;
  for (int j = 1; j <= it; j++) {
    float pr = sqrtf((float)hp[j - 1]), dr = sqrtf((float)hd[j - 1]);
    done |= (pr < 1e-4f && dr < 1e-4f);
    if (done) { d = j; break; }
  }
  return d & 1;
}

// 320-pt FFT core, 320 threads (1 point each), mixed radix 5*4*4*4.
// IN natural order; RETURNS output element oidx(t) in registers. SCR wave-private.
// Caller syncs after filling IN; must not overwrite IN until a later block sync.
// MASKED: multiply result by misRow[oidx(t)] (prefetched at entry).
template <int SIGN, bool MASKED>
__device__ C2 fftp_core(const float2* IN, float2* SCR, const float2* tw, int t,
                        const float* __restrict__ misRow) {
  const int q = t >> 6, n1 = t & 63;
  float2* lo = SCR + q * 128;
  float2* hi = lo + 64;
  float mval = 1.f;
  if (MASKED) mval = misRow[5 * n1 + q];
  C2 acc;
  {  // radix-5 over stride-64 (cross-wave reads of IN) + twiddle w320^{n1 q}
    float2 v0 = IN[n1];
    acc.x = v0.x; acc.y = v0.y;
#pragma unroll
    for (int n2 = 1; n2 < 5; n2++) {
      float2 v = IN[n1 + 64 * n2];
      C2 w = TW<SIGN>(tw, 64 * ((n2 * q) % 5));
      acc.x += v.x * w.x - v.y * w.y;
      acc.y += v.x * w.y + v.y * w.x;
    }
    acc = cmul(acc, TW<SIGN>(tw, n1 * q));
  }
  lo[n1] = make_float2(acc.x, acc.y);
  wavebar();
  {  // radix-4, Lr=4 : lo -> hi (wave-private)
    C2 s{0.f, 0.f};
    int rr = n1 & 3, base = n1 >> 2;
#pragma unroll
    for (int p = 0; p < 4; p++) {
      float2 v = lo[base + 16 * p];
      C2 w = TW<SIGN>(tw, 80 * ((p * rr) & 3));
      s.x += v.x * w.x - v.y * w.y;
      s.y += v.x * w.y + v.y * w.x;
    }
    hi[n1] = make_float2(s.x, s.y);
  }
  wavebar();
  {  // radix-4, Lr=16 : hi -> lo (wave-private)
    C2 s{0.f, 0.f};
    int rr = n1 & 15, base = ((n1 >> 4) << 2) + (n1 & 3);
#pragma unroll
    for (int p = 0; p < 4; p++) {
      float2 v = hi[base + 16 * p];
      C2 w = TW<SIGN>(tw, 20 * ((p * rr) & 15));
      s.x += v.x * w.x - v.y * w.y;
      s.y += v.x * w.y + v.y * w.x;
    }
    lo[n1] = make_float2(s.x, s.y);
  }
  wavebar();
  {  // radix-4, Lr=64 : lo -> element 5*n1+q (registers)
    C2 s{0.f, 0.f};
    int base = n1 & 15;
#pragma unroll
    for (int p = 0; p < 4; p++) {
      float2 v = lo[base + 16 * p];
      C2 w = TW<SIGN>(tw, 5 * ((p * n1) & 63));
      s.x += v.x * w.x - v.y * w.y;
      s.y += v.x * w.y + v.y * w.x;
    }
    acc = s;
  }
  if (MASKED) { acc.x *= mval; acc.y *= mval; }
  return acc;
}

// G(z) = div_x(dx z_re) + div_y(dx z_im), interleaved complex z
DEVFN float Gfunc2(const float2* __restrict__ z, int b, int h, int w) {
  const float2* zz = z + b * NHW;
  int hw = h * NW + w;
  float divx, divy;
  if (w == 0) {
    divx = zz[hw + 1].x - zz[hw].x;
  } else if (w < NW - 1) {
    divx = (zz[hw + 1].x - zz[hw].x) - (zz[hw].x - zz[hw - 1].x);
  } else {
    divx = -(zz[hw].x - zz[hw - 1].x);
  }
  if (h == 0) {
    divy = (w < NW - 1) ? zz[hw + 1].y - zz[hw].y : 0.f;
  } else if (h < NH - 1) {
    float a = (w < NW - 1) ? zz[hw + 1].y - zz[hw].y : 0.f;
    float bb = (w < NW - 1) ? zz[hw - NW + 1].y - zz[hw - NW].y : 0.f;
    divy = a - bb;
  } else {
    divy = -((w < NW - 1) ? zz[hw - NW + 1].y - zz[hw - NW].y : 0.f);
  }
  return divx + divy;
}

// b-term: div_x((u-v)_ch0) + div_y((u-v)_ch1)   (u, v planar 4-channel real)
DEVFN float divUV(const float* __restrict__ u, const float* __restrict__ v, int b, int h, int w) {
  const float* u0 = u + (b * 4 + 0) * NHW; const float* v0 = v + (b * 4 + 0) * NHW;
  const float* u1 = u + (b * 4 + 1) * NHW; const float* v1 = v + (b * 4 + 1) * NHW;
  int hw = h * NW + w;
  float divx, divy;
  if (w == 0)          divx = u0[hw] - v0[hw];
  else if (w < NW - 1) divx = (u0[hw] - v0[hw]) - (u0[hw - 1] - v0[hw - 1]);
  else                 divx = -(u0[hw - 1] - v0[hw - 1]);
  if (h == 0)          divy = u1[hw] - v1[hw];
  else if (h < NH - 1) divy = (u1[hw] - v1[hw]) - (u1[hw - NW] - v1[hw - NW]);
  else                 divy = -(u1[hw - NW] - v1[hw - NW]);
  return divx + divy;
}

DEVFN double shflxd(double v, int m) {
  union { double d; int i[2]; } a; a.d = v;
  a.i[0] = __shfl_xor(a.i[0], m, 64);
  a.i[1] = __shfl_xor(a.i[1], m, 64);
  return a.d;
}
DEVFN double waveRed(double v) {
#pragma unroll
  for (int m = 32; m; m >>= 1) v += shflxd(v, m);
  return v;
}

// reduce 1280 per-block partials -> scalar, broadcast (deterministic fixed order)
__device__ double redParts(const double* __restrict__ part, double* sdot, int t) {
  double v = part[t] + part[t + 320] + part[t + 640] + part[t + 960];
  v = waveRed(v);
  if ((t & 63) == 0) sdot[t >> 6] = v;
  __syncthreads();
  double s = sdot[0] + sdot[1] + sdot[2] + sdot[3] + sdot[4];
  __syncthreads();
  return s;
}

// reduce packed triple partials part3[blk*3+{0,1,2}] -> 3 scalars, broadcast
__device__ void redParts3(const double* __restrict__ part3, double* sdot, int t,
                          double& o0, double& o1, double& o2) {
  double s0 = 0, s1 = 0, s2 = 0;
#pragma unroll
  for (int j = 0; j < 4; j++) {
    int blk = t + j * 320;
    s0 += part3[blk * 3 + 0];
    s1 += part3[blk * 3 + 1];
    s2 += part3[blk * 3 + 2];
  }
  s0 = waveRed(s0); s1 = waveRed(s1); s2 = waveRed(s2);
  int wv = t >> 6;
  if ((t & 63) == 0) { sdot[wv * 3] = s0; sdot[wv * 3 + 1] = s1; sdot[wv * 3 + 2] = s2; }
  __syncthreads();
  double a0 = 0, a1 = 0, a2 = 0;
#pragma unroll
  for (int w2 = 0; w2 < 5; w2++) { a0 += sdot[w2 * 3]; a1 += sdot[w2 * 3 + 1]; a2 += sdot[w2 * 3 + 2]; }
  __syncthreads();
  o0 = a0; o1 = a1; o2 = a2;
}

__device__ void blockDot1(double a, double* sdot, int t, double* outp) {
  a = waveRed(a);
  if ((t & 63) == 0) sdot[t >> 6] = a;
  __syncthreads();
  if (t == 0) *outp = sdot[0] + sdot[1] + sdot[2] + sdot[3] + sdot[4];
  __syncthreads();
}

// packed write: o3[bid*3 + {0,1,2}]
__device__ void blockDot3p(double a, double b, double c, double* sdot, int t,
                           double* o3, int bid) {
  a = waveRed(a); b = waveRed(b); c = waveRed(c);
  int wv = t >> 6;
  if ((t & 63) == 0) { sdot[wv * 3] = a; sdot[wv * 3 + 1] = b; sdot[wv * 3 + 2] = c; }
  __syncthreads();
  if (t == 0) {
    double s0 = 0, s1 = 0, s2 = 0;
#pragma unroll
    for (int w2 = 0; w2 < 5; w2++) { s0 += sdot[w2 * 3]; s1 += sdot[w2 * 3 + 1]; s2 += sdot[w2 * 3 + 2]; }
    o3[bid * 3 + 0] = s0; o3[bid * 3 + 1] = s1; o3[bid * 3 + 2] = s2;
  }
  __syncthreads();
}

#define FFTK_SHARED                                     \
  __shared__ float2 sA[320];                            \
  __shared__ float2 sB[320];                            \
  __shared__ float2 sS[640];                            \
  __shared__ float2 stw[320];                           \
  __shared__ double sdot[16];                           \
  (void)sdot;                                           \
  const int t = threadIdx.x;                            \
  const int bid = blockIdx.x;                           \
  stw[t] = twg[t];

// Handoff rule (double-buffered transpose): every FFT kernel READS its line
// contiguously from one buffer and WRITES the OTHER buffer transposed.
// u/v ping-pong: commit(it) writes buf[(it+1)&1] guarded by !done_before(it);
// consumers resolve parity via uvParity(it).

// ---------------- kernels (grid = 1280 x 320 everywhere) ----------------

// twiddle table + transposed shifted/scaled mask misT[b][w][h]
__global__ __launch_bounds__(NTHR) void k_init(const float* __restrict__ mask,
                                               float* __restrict__ misT, float2* __restrict__ tw) {
  int t = threadIdx.x, bid = blockIdx.x;
  if (bid == 0) {
    double ang = -2.0 * 3.14159265358979323846 * (double)t / 320.0;
    tw[t] = make_float2((float)cos(ang), (float)sin(ang));
  }
  int i = bid * NTHR + t;  // exactly NB*NHW
  int b = i / NHW, hw = i % NHW, h = hw / NW, w = hw % NW;
  int hs = (h + 160) % 320, ws = (w + 160) % 320;
  misT[b * NHW + w * NW + h] = mask[b * NHW + hs * NW + ws] * (1.0f / 102400.0f);
}

// rows S*IFFT*S of y -> tA(T) and of mask*y -> tB(T) (y planar input). Swizzled.
__global__ __launch_bounds__(NTHR) void k0a(const float* __restrict__ y, const float* __restrict__ mask,
                                            float2* __restrict__ tA, float2* __restrict__ tB,
                                            const float2* __restrict__ twg) {
  FFTK_SHARED
  const int wid = swzcol(bid);
  const int gb = wid / NH, gl = wid % NH;
  const int rowBase = gb * NC2 + gl * NW;
  float sgn = (t & 1) ? -1.f : 1.f;
  sA[t] = make_float2(sgn * y[rowBase + t], sgn * y[rowBase + NHW + t]);
  __syncthreads();
  C2 a1 = fftp_core<1, false>(sA, sS, stw, t, nullptr);
  const int o = oidx(t);
  const float sgo = (o & 1) ? -1.f : 1.f;
  tA[gb * NHW + o * NW + gl] = make_float2(sgo * a1.x, sgo * a1.y);
  __syncthreads();
  float m = mask[gb * NHW + gl * NW + t];
  sA[t] = make_float2(sgn * m * y[rowBase + t], sgn * m * y[rowBase + NHW + t]);
  __syncthreads();
  C2 a2 = fftp_core<1, false>(sA, sS, stw, t, nullptr);
  tB[gb * NHW + o * NW + gl] = make_float2(sgo * a2.x, sgo * a2.y);
}

// cols S*IFFT*S (scale 1/320): tA -> x2, tB -> bdata2 (interleaved spatial). Swizzled.
__global__ __launch_bounds__(NTHR) void k0b(const float2* __restrict__ tA, const float2* __restrict__ tB,
                                            float2* __restrict__ x2, float2* __restrict__ bdata2,
                                            const float2* __restrict__ twg) {
  FFTK_SHARED
  const int wid = swzcol(bid);
  const int gb = wid / NH, gl = wid % NH;
  float sgn = (t & 1) ? -1.f : 1.f;
  {
    float2 v = tA[gb * NHW + gl * NW + t];
    sA[t] = make_float2(sgn * v.x, sgn * v.y);
  }
  __syncthreads();
  C2 a1 = fftp_core<1, false>(sA, sS, stw, t, nullptr);
  const int o = oidx(t);
  const float so = ((o & 1) ? -1.f : 1.f) * (1.f / 320.f);
  x2[gb * NHW + o * NW + gl] = make_float2(a1.x * so, a1.y * so);
  __syncthreads();
  {
    float2 v = tB[gb * NHW + gl * NW + t];
    sA[t] = make_float2(sgn * v.x, sgn * v.y);
  }
  __syncthreads();
  C2 a2 = fftp_core<1, false>(sA, sS, stw, t, nullptr);
  bdata2[gb * NHW + o * NW + gl] = make_float2(a2.x * so, a2.y * so);
}

// u0 = gradient(x), v0 = 0 (1 site/thread, raw bid); xc = x; rowFFT(x) -> tA(T). Swizzled FFT.
__global__ __launch_bounds__(NTHR) void ka0(const float2* __restrict__ x2, float2* __restrict__ xc2,
                                            float* __restrict__ u0, float* __restrict__ v0,
                                            float2* __restrict__ tA, const float2* __restrict__ twg) {
  FFTK_SHARED
  const int wid = swzcol(bid);
  const int gb = wid / NH, gl = wid % NH;
  {
    int i = bid * NTHR + t;
    int b = i / NHW, hw = i % NHW, h = hw / NW, w = hw % NW;
    const float2* zz = x2 + b * NHW;
    float2 z0 = zz[hw];
    float g0 = 0, g1 = 0, g2 = 0, g3 = 0;
    if (w < NW - 1) { float2 zr = zz[hw + 1]; g0 = zr.x - z0.x; g1 = zr.y - z0.y; }
    if (h < NH - 1) { float2 zd = zz[hw + NW]; g2 = zd.x - z0.x; g3 = zd.y - z0.y; }
    int b4 = b * 4 * NHW;
    u0[b4 + hw] = g0;           v0[b4 + hw] = 0.f;
    u0[b4 + NHW + hw] = g1;     v0[b4 + NHW + hw] = 0.f;
    u0[b4 + 2 * NHW + hw] = g2; v0[b4 + 2 * NHW + hw] = 0.f;
    u0[b4 + 3 * NHW + hw] = g3; v0[b4 + 3 * NHW + hw] = 0.f;
  }
  int idx = gb * NHW + gl * NW + t;
  float2 xv = x2[idx];
  xc2[idx] = xv;
  sA[t] = xv;
  __syncthreads();
  C2 a = fftp_core<-1, false>(sA, sS, stw, t, nullptr);
  tA[gb * NHW + oidx(t) * NW + gl] = make_float2(a.x, a.y);
}

// [it>0: reduce prev pres/dres -> hist] ; colFM: tA -> tB. Swizzled. (no commit copy)
__global__ __launch_bounds__(NTHR) void kb(const float2* __restrict__ tA, float2* __restrict__ tB,
                                           const float* __restrict__ misT,
                                           const double* __restrict__ pPaPrev, const double* __restrict__ pPbPrev,
                                           double* __restrict__ hist_pres, double* __restrict__ hist_dres,
                                           const float2* __restrict__ twg, int it) {
  FFTK_SHARED
  const int wid = swzcol(bid);
  const int gb = wid / NH, gl = wid % NH;
  if (it > 0) {
    double ppa = redParts(pPaPrev, sdot, t);
    double ppb = redParts(pPbPrev, sdot, t);
    if (bid == 0 && t == 0) { hist_pres[it - 1] = ppa; hist_dres[it - 1] = ppb; }
  }
  sA[t] = tA[gb * NHW + gl * NW + t];
  __syncthreads();
  C2 a1 = fftp_core<-1, true>(sA, sS, stw, t, misT + gb * NHW + gl * NW);
  const int o = oidx(t);
  sB[o] = make_float2(a1.x, a1.y);
  __syncthreads();
  C2 a2 = fftp_core<1, false>(sB, sS, stw, t, nullptr);
  tB[gb * NHW + o * NW + gl] = make_float2(a2.x, a2.y);
}

// rowIFFT(tB) -> A(x); r = p = (bdata + divUV) - A(x); rsold partials; rowFFT(p) -> tA(T). Swizzled.
__global__ __launch_bounds__(NTHR) void kcd(const float2* __restrict__ tB, float2* __restrict__ tA,
                                            const float2* __restrict__ x2,
                                            const float* __restrict__ ub0, const float* __restrict__ ub1,
                                            const float* __restrict__ vb0, const float* __restrict__ vb1,
                                            const float2* __restrict__ bdata2, float2* __restrict__ r2,
                                            float2* __restrict__ p2, double* __restrict__ pRS,
                                            const double* __restrict__ hist_pres,
                                            const double* __restrict__ hist_dres,
                                            const float2* __restrict__ twg, int it) {
  FFTK_SHARED
  const int wid = swzcol(bid);
  const int gb = wid / NH, gl = wid % NH;
  const int P = uvParity(hist_pres, hist_dres, it);
  const float* u = P ? ub1 : ub0;
  const float* v = P ? vb1 : vb0;
  sA[t] = tB[gb * NHW + gl * NW + t];
  __syncthreads();
  C2 a1 = fftp_core<1, false>(sA, sS, stw, t, nullptr);
  const int o = oidx(t);
  const int idxO = gb * NHW + gl * NW + o;
  float G = Gfunc2(x2, gb, gl, o);
  float d = divUV(u, v, gb, gl, o);
  float2 bd = bdata2[idxO];
  float rr = (bd.x + d) - (a1.x - G);
  float ri = (bd.y + d) - (a1.y - G);
  float2 rv = make_float2(rr, ri);
  r2[idxO] = rv; p2[idxO] = rv;
  double acc = (double)rr * rr + (double)ri * ri;
  blockDot1(acc, sdot, t, &pRS[bid]);   // internal syncs: sA reads complete
  sA[o] = rv;                           // natural-order restage of p
  __syncthreads();
  C2 a2 = fftp_core<-1, false>(sA, sS, stw, t, nullptr);
  tA[gb * NHW + o * NW + gl] = make_float2(a2.x, a2.y);
}

// k>=1: reduce dots (packed); update xc, r, p; rowFFT(p) -> tA(T). Swizzled.
__global__ __launch_bounds__(NTHR) void kd(float2* __restrict__ xc2, float2* __restrict__ r2,
                                           float2* __restrict__ p2, const float2* __restrict__ Ap2,
                                           float2* __restrict__ tA, const double* __restrict__ pRS,
                                           const double* __restrict__ pD3, double* __restrict__ hist_rs,
                                           const float2* __restrict__ twg, int k) {
  FFTK_SHARED
  const int wid = swzcol(bid);
  const int gb = wid / NH, gl = wid % NH;
  const int idx = gb * NHW + gl * NW + t;
  double pAp, rAp, A2;
  redParts3(pD3, sdot, t, pAp, rAp, A2);
  double rsold = (k == 1) ? redParts(pRS, sdot, t) : hist_rs[k - 2];
  float alpha = (float)rsold / ((float)pAp + 1e-12f);
  // exact algebraic expansion of ||r - alpha*Ap||^2 (no conjugacy assumption)
  double rsnew = rsold - 2.0 * (double)alpha * rAp + (double)alpha * (double)alpha * A2;
  if (bid == 0 && t == 0) hist_rs[k - 1] = rsnew;
  bool doneIn = false;
  for (int j = 0; j <= k - 2; j++) doneIn |= ((float)hist_rs[j] < 1e-10f);
  bool stop = ((float)rsnew < 1e-10f);
  bool doneP = doneIn || stop;
  float beta = (float)rsnew / (float)rsold;
  float2 pv = p2[idx], rv = r2[idx], av = Ap2[idx], xv = xc2[idx];
  if (!doneIn) {
    xv.x += alpha * pv.x; xv.y += alpha * pv.y;
    rv.x -= alpha * av.x; rv.y -= alpha * av.y;
  }
  float2 pn = doneP ? pv : make_float2(rv.x + beta * pv.x, rv.y + beta * pv.y);
  xc2[idx] = xv; r2[idx] = rv; p2[idx] = pn;
  sA[t] = pn;
  __syncthreads();
  C2 a = fftp_core<-1, false>(sA, sS, stw, t, nullptr);
  tA[gb * NHW + oidx(t) * NW + gl] = make_float2(a.x, a.y);
}

// plain colFM (mask fused into forward FFT tail): tA -> tB. Swizzled.
__global__ __launch_bounds__(NTHR) void ke(const float2* __restrict__ tA, float2* __restrict__ tB,
                                           const float* __restrict__ misT,
                                           const float2* __restrict__ twg) {
  FFTK_SHARED
  const int wid = swzcol(bid);
  const int gb = wid / NH, gl = wid % NH;
  sA[t] = tA[gb * NHW + gl * NW + t];
  __syncthreads();
  C2 a1 = fftp_core<-1, true>(sA, sS, stw, t, misT + gb * NHW + gl * NW);
  const int o = oidx(t);
  sB[o] = make_float2(a1.x, a1.y);
  __syncthreads();
  C2 a2 = fftp_core<1, false>(sB, sS, stw, t, nullptr);
  tB[gb * NHW + o * NW + gl] = make_float2(a2.x, a2.y);
}

// rowIFFT(tB) -> Ap = M(p) - G(p); packed dots p.Ap, r.Ap, Ap.Ap. Swizzled.
__global__ __launch_bounds__(NTHR) void kf(const float2* __restrict__ tB, const float2* __restrict__ p2,
                                           const float2* __restrict__ r2, float2* __restrict__ Ap2,
                                           double* __restrict__ pD3, const float2* __restrict__ twg) {
  FFTK_SHARED
  const int wid = swzcol(bid);
  const int gb = wid / NH, gl = wid % NH;
  sA[t] = tB[gb * NHW + gl * NW + t];
  __syncthreads();
  C2 a = fftp_core<1, false>(sA, sS, stw, t, nullptr);
  const int o = oidx(t);
  const int idxO = gb * NHW + gl * NW + o;
  float G = Gfunc2(p2, gb, gl, o);
  float Ar = a.x - G, Ai = a.y - G;
  Ap2[idxO] = make_float2(Ar, Ai);
  float2 pv = p2[idxO], rv = r2[idxO];
  double aP = (double)pv.x * Ar + (double)pv.y * Ai;
  double aR = (double)rv.x * Ar + (double)rv.y * Ai;
  double aA = (double)Ar * Ar + (double)Ai * Ai;
  blockDot3p(aP, aR, aA, sdot, t, pD3, bid);
}

// final CG x-update; xn -> tB (spatial); guarded DIRECT u/v commit into
// buf[(it+1)&1]; pres partials. 1 site/thread.
__global__ __launch_bounds__(NTHR) void kh1(const float2* __restrict__ xc2, const float2* __restrict__ p2,
                                            float* __restrict__ ub0, float* __restrict__ ub1,
                                            float* __restrict__ vb0, float* __restrict__ vb1,
                                            float2* __restrict__ tB,
                                            const double* __restrict__ pD3, const double* __restrict__ hist_rs,
                                            const double* __restrict__ hist_pres,
                                            const double* __restrict__ hist_dres,
                                            double* __restrict__ pPaCur, int it) {
  __shared__ double sdot[16];
  const int t = threadIdx.x, bid = blockIdx.x;
  double pAp, rApU, A2U;
  redParts3(pD3, sdot, t, pAp, rApU, A2U);
  (void)rApU; (void)A2U;
  double rsold = hist_rs[8];
  float alphaF = (float)rsold / ((float)pAp + 1e-12f);
  bool doneX = false;
  for (int j = 0; j <= 8; j++) doneX |= ((float)hist_rs[j] < 1e-10f);
  const bool doneA = doneBefore(hist_pres, hist_dres, it);
  const int P = uvParity(hist_pres, hist_dres, it);
  const float* vrd = P ? vb1 : vb0;
  float* uwr = ((it + 1) & 1) ? ub1 : ub0;
  float* vwr = ((it + 1) & 1) ? vb1 : vb0;
  int i = bid * NTHR + t;
  int b = i / NHW, hw = i % NHW, h = hw / NW, w = hw % NW;
  int base2 = b * NHW;
  auto XN = [&](int off) {
    float2 vv = xc2[base2 + off];
    if (!doneX) {
      float2 pp = p2[base2 + off];
      vv.x += alphaF * pp.x; vv.y += alphaF * pp.y;
    }
    return vv;
  };
  float2 x0 = XN(hw);
  float g0 = 0, g1 = 0, g2 = 0, g3 = 0;
  if (w < NW - 1) { float2 xr = XN(hw + 1); g0 = xr.x - x0.x; g1 = xr.y - x0.y; }
  if (h < NH - 1) { float2 xd = XN(hw + NW); g2 = xd.x - x0.x; g3 = xd.y - x0.y; }
  tB[base2 + hw] = x0;
  float gs[4] = {g0, g1, g2, g3};
  double acc = 0.0;
#pragma unroll
  for (int ch = 0; ch < 4; ch++) {
    int ui = (b * 4 + ch) * NHW + hw;
    float vv = vrd[ui];
    float sv = gs[ch] + vv;
    float a2 = fabsf(sv) - THRESHc;
    float uo = (a2 > 0.f) ? copysignf(a2, sv) : 0.f;
    if (!doneA) {
      uwr[ui] = uo;
      vwr[ui] = vv + gs[ch] - uo;
    }
    float dd = gs[ch] - uo;
    acc += (double)dd * dd;
  }
  blockDot1(acc, sdot, t, &pPaCur[bid]);
}

// dres partials (raw bid): un = ub[(it+1)&1] vs u_old = ub[P]; guarded x commit
// from tB(xn spatial); rowFFT(x) -> tA(T). Swizzled FFT.
__global__ __launch_bounds__(NTHR) void kh2a(float2* __restrict__ x2, float2* __restrict__ xc2,
                                             const float2* __restrict__ tB, float2* __restrict__ tA,
                                             const float* __restrict__ ub0, const float* __restrict__ ub1,
                                             const double* __restrict__ hist_pres,
                                             const double* __restrict__ hist_dres,
                                             double* __restrict__ pPbCur,
                                             const float2* __restrict__ twg, int it) {
  FFTK_SHARED
  const int wid = swzcol(bid);
  const int gb = wid / NH, gl = wid % NH;
  const int idx = gb * NHW + gl * NW + t;
  const bool doneA = doneBefore(hist_pres, hist_dres, it);
  const int P = uvParity(hist_pres, hist_dres, it);
  const float* un = ((it + 1) & 1) ? ub1 : ub0;
  const float* uo = P ? ub1 : ub0;
  {
    int i = bid * NTHR + t;
    int b = i / NHW, hw = i % NHW, h = hw / NW, w = hw % NW;
    const float* N0 = un + (b * 4 + 0) * NHW; const float* U0 = uo + (b * 4 + 0) * NHW;
    const float* N1 = un + (b * 4 + 1) * NHW; const float* U1 = uo + (b * 4 + 1) * NHW;
    float divx, divy;
    if (w == 0)          divx = N0[hw] - U0[hw];
    else if (w < NW - 1) divx = (N0[hw] - U0[hw]) - (N0[hw - 1] - U0[hw - 1]);
    else                 divx = -(N0[hw - 1] - U0[hw - 1]);
    if (h == 0)          divy = N1[hw] - U1[hw];
    else if (h < NH - 1) divy = (N1[hw] - U1[hw]) - (N1[hw - NW] - U1[hw - NW]);
    else                 divy = -(N1[hw - NW] - U1[hw - NW]);
    float d = divx + divy;
    double acc = (double)d * d;
    blockDot1(acc, sdot, t, &pPbCur[bid]);
  }
  float2 xn = tB[idx];
  float2 xf = doneA ? x2[idx] : xn;
  x2[idx] = xf; xc2[idx] = xf;
  sA[t] = xf;
  __syncthreads();
  C2 a = fftp_core<-1, false>(sA, sS, stw, t, nullptr);
  tA[gb * NHW + oidx(t) * NW + gl] = make_float2(a.x, a.y);
}

__global__ __launch_bounds__(NTHR) void k_out(const float2* __restrict__ x2,
                                              const double* __restrict__ hist_pres,
                                              const double* __restrict__ hist_dres,
                                              const double* __restrict__ pPa9,
                                              const double* __restrict__ pPb9,
                                              float* __restrict__ out) {
  __shared__ double sdot[16];
  const int t = threadIdx.x, bid = blockIdx.x;
  {
    int i = bid * NTHR + t;  // exactly NB*NHW sites
    int b = i / NHW, hw = i % NHW;
    float2 v = x2[b * NHW + hw];
    out[b * NC2 + hw] = v.x;
    out[b * NC2 + NHW + hw] = v.y;
  }
  if (bid == 0) {
    double p9 = redParts(pPa9, sdot, t);
    double d9 = redParts(pPb9, sdot, t);
    if (t == 0) {
      int count = 0; bool done = false; float presO = 0.f, dresO = 0.f;
      for (int it = 0; it < 10; ++it) {
        double hp = (it == 9) ? p9 : hist_pres[it];
        double hd = (it == 9) ? d9 : hist_dres[it];
        if (!done) {
          count++;
          presO = sqrtf((float)hp);
          dresO = sqrtf((float)hd);
          done = (presO < 1e-4f) && (dresO < 1e-4f);
        }
      }
      out[NB * NC2 + 0] = (float)count;
      out[NB * NC2 + 1] = presO;
      out[NB * NC2 + 2] = dresO;
    }
  }
}

}  // namespace

extern "C" void kernel_launch(void* const* d_in, const int* in_sizes, int n_in,
                              void* d_out, int out_size, void* d_ws, size_t ws_size,
                              hipStream_t stream) {
  (void)in_sizes; (void)n_in; (void)out_size; (void)ws_size;
  const float* y = (const float*)d_in[0];
  const float* mask = (const float*)d_in[1];
  float* out = (float*)d_out;
  float* wsf = (float*)d_ws;

  double* dws = (double*)wsf;
  double* pRS       = dws;           // 1280
  double* pD3       = dws + 1280;    // 3840 packed (pAp, rAp, ApAp per block)
  double* pPa       = dws + 5120;    // 2 x 1280 (parity)
  double* pPb       = dws + 7680;    // 2 x 1280 (parity)
  double* hist_rs   = dws + 10240;   // 16
  double* hist_pres = dws + 10256;   // 16
  double* hist_dres = dws + 10272;   // 16 -> ends at 10288 doubles

  float* fb = wsf + 20576;           // after 10288 doubles
  float2* tw = (float2*)fb; fb += 640;
  float* misT = fb; fb += (size_t)NB * NHW;
  float2* tA = (float2*)fb; fb += (size_t)2 * NB * NHW;
  float2* tB = (float2*)fb; fb += (size_t)2 * NB * NHW;
  auto take2 = [&](size_t n) { float2* ptr = (float2*)fb; fb += 2 * n; return ptr; };
  float2* x2     = take2((size_t)NB * NHW);
  float2* xc2    = take2((size_t)NB * NHW);
  float2* r2     = take2((size_t)NB * NHW);
  float2* p2     = take2((size_t)NB * NHW);
  float2* Ap2    = take2((size_t)NB * NHW);
  float2* bdata2 = take2((size_t)NB * NHW);
  auto take = [&](size_t n) { float* ptr = fb; fb += n; return ptr; };
  float* u0 = take((size_t)NB * 4 * NHW);
  float* u1 = take((size_t)NB * 4 * NHW);
  float* v0 = take((size_t)NB * 4 * NHW);
  float* v1 = take((size_t)NB * 4 * NHW);

  k_init<<<GRID, NTHR, 0, stream>>>(mask, misT, tw);
  k0a<<<GRID, NTHR, 0, stream>>>(y, mask, tA, tB, tw);
  k0b<<<GRID, NTHR, 0, stream>>>(tA, tB, x2, bdata2, tw);
  ka0<<<GRID, NTHR, 0, stream>>>(x2, xc2, u0, v0, tA, tw);

  for (int it = 0; it < 10; ++it) {
    int prevPar = (it + 1) & 1;  // (it-1)&1
    int curPar = it & 1;
    kb<<<GRID, NTHR, 0, stream>>>(tA, tB, misT,
                                  pPa + prevPar * 1280, pPb + prevPar * 1280,
                                  hist_pres, hist_dres, tw, it);
    kcd<<<GRID, NTHR, 0, stream>>>(tB, tA, x2, u0, u1, v0, v1, bdata2, r2, p2, pRS,
                                   hist_pres, hist_dres, tw, it);
    ke<<<GRID, NTHR, 0, stream>>>(tA, tB, misT, tw);
    kf<<<GRID, NTHR, 0, stream>>>(tB, p2, r2, Ap2, pD3, tw);
    for (int k = 1; k < 10; ++k) {
      kd<<<GRID, NTHR, 0, stream>>>(xc2, r2, p2, Ap2, tA, pRS, pD3, hist_rs, tw, k);
      ke<<<GRID, NTHR, 0, stream>>>(tA, tB, misT, tw);
      kf<<<GRID, NTHR, 0, stream>>>(tB, p2, r2, Ap2, pD3, tw);
    }
    kh1<<<GRID, NTHR, 0, stream>>>(xc2, p2, u0, u1, v0, v1, tB, pD3, hist_rs,
                                   hist_pres, hist_dres, pPa + curPar * 1280, it);
    kh2a<<<GRID, NTHR, 0, stream>>>(x2, xc2, tB, tA, u0, u1, hist_pres, hist_dres,
                                    pPb + curPar * 1280, tw, it);
  }
  k_out<<<GRID, NTHR, 0, stream>>>(x2, hist_pres, hist_dres, pPa + 1280, pPb + 1280, out);
}

// Round 16
// 2681.556 us; speedup vs baseline: 1.0101x; 1.0101x over previous
//
#include <hip/hip_runtime.h>
#include <math.h>

#define DEVFN __device__ __forceinline__

namespace {

constexpr int NW = 320, NH = 320, NHW = NW * NH, NB = 4;
constexpr int NC2 = 2 * NHW;          // floats per complex image
constexpr int GRID = NB * NH;         // 1280 blocks (one line per block)
constexpr int NTHR = 320;             // one point per thread
constexpr float THRESHc = 0.01f;      // LAMBDA_TV / RHO

struct C2 { float x, y; };
DEVFN C2 cmul(C2 a, C2 b) { return C2{a.x * b.x - a.y * b.y, a.x * b.y + a.y * b.x}; }

template <int SIGN>
DEVFN C2 TW(const float2* tw, int m) {
  float2 t = tw[m];
  return C2{t.x, (SIGN < 0) ? t.y : -t.y};
}

// XCD-chunked swizzle (ALL FFT kernels): adjacent lines -> same XCD L2, so the
// transposed 8B/line writes of 8 neighboring blocks merge into full 64B lines.
DEVFN int swzcol(int bid) { return (bid & 7) * (GRID / 8) + (bid >> 3); }

// thread t computes FFT output element oidx(t)
DEVFN int oidx(int t) { return 5 * (t & 63) + (t >> 6); }

// compiler fence for wave-synchronous LDS (wave64 lockstep; LDS in-order per wave)
DEVFN void wavebar() {
  __builtin_amdgcn_wave_barrier();
  asm volatile("" ::: "memory");
}

// 320-pt FFT core, 320 threads (1 point each), mixed radix 5*4*4*4.
// IN natural order; RETURNS output element oidx(t) in registers (no LDS scatter,
// no trailing sync). SCR = 640-float2 wave-private scratch. Caller must
// __syncthreads() after filling IN, and must NOT overwrite IN until a
// subsequent block-wide sync. Radix-4 stages are wave-private (wavebar only).
// MASKED: multiply result by misRow[oidx(t)] (prefetched at entry).
template <int SIGN, bool MASKED>
__device__ C2 fftp_core(const float2* IN, float2* SCR, const float2* tw, int t,
                        const float* __restrict__ misRow) {
  const int q = t >> 6, n1 = t & 63;
  float2* lo = SCR + q * 128;
  float2* hi = lo + 64;
  float mval = 1.f;
  if (MASKED) mval = misRow[5 * n1 + q];  // prefetch; used after 4 stages
  C2 acc;
  {  // radix-5 over stride-64 (cross-wave reads of IN) + twiddle w320^{n1 q}
    float2 v0 = IN[n1];
    acc.x = v0.x; acc.y = v0.y;
#pragma unroll
    for (int n2 = 1; n2 < 5; n2++) {
      float2 v = IN[n1 + 64 * n2];
      C2 w = TW<SIGN>(tw, 64 * ((n2 * q) % 5));
      acc.x += v.x * w.x - v.y * w.y;
      acc.y += v.x * w.y + v.y * w.x;
    }
    acc = cmul(acc, TW<SIGN>(tw, n1 * q));  // n1*q <= 252 < 320
  }
  lo[n1] = make_float2(acc.x, acc.y);
  wavebar();
  {  // radix-4, Lr=4 (w4 = tw[80*..]) : lo -> hi (wave-private)
    C2 s{0.f, 0.f};
    int rr = n1 & 3, base = n1 >> 2;
#pragma unroll
    for (int p = 0; p < 4; p++) {
      float2 v = lo[base + 16 * p];
      C2 w = TW<SIGN>(tw, 80 * ((p * rr) & 3));
      s.x += v.x * w.x - v.y * w.y;
      s.y += v.x * w.y + v.y * w.x;
    }
    hi[n1] = make_float2(s.x, s.y);
  }
  wavebar();
  {  // radix-4, Lr=16 (w16 = tw[20*..]) : hi -> lo (wave-private)
    C2 s{0.f, 0.f};
    int rr = n1 & 15, base = ((n1 >> 4) << 2) + (n1 & 3);
#pragma unroll
    for (int p = 0; p < 4; p++) {
      float2 v = hi[base + 16 * p];
      C2 w = TW<SIGN>(tw, 20 * ((p * rr) & 15));
      s.x += v.x * w.x - v.y * w.y;
      s.y += v.x * w.y + v.y * w.x;
    }
    lo[n1] = make_float2(s.x, s.y);
  }
  wavebar();
  {  // radix-4, Lr=64 (w64 = tw[5*..]) : lo -> element 5*n1+q (registers)
    C2 s{0.f, 0.f};
    int base = n1 & 15;
#pragma unroll
    for (int p = 0; p < 4; p++) {
      float2 v = lo[base + 16 * p];
      C2 w = TW<SIGN>(tw, 5 * ((p * n1) & 63));
      s.x += v.x * w.x - v.y * w.y;
      s.y += v.x * w.y + v.y * w.x;
    }
    acc = s;
  }
  if (MASKED) { acc.x *= mval; acc.y *= mval; }
  return acc;
}

// G(z) = div_x(dx z_re) + div_y(dx z_im), interleaved complex z
DEVFN float Gfunc2(const float2* __restrict__ z, int b, int h, int w) {
  const float2* zz = z + b * NHW;
  int hw = h * NW + w;
  float divx, divy;
  if (w == 0) {
    divx = zz[hw + 1].x - zz[hw].x;
  } else if (w < NW - 1) {
    divx = (zz[hw + 1].x - zz[hw].x) - (zz[hw].x - zz[hw - 1].x);
  } else {
    divx = -(zz[hw].x - zz[hw - 1].x);
  }
  if (h == 0) {
    divy = (w < NW - 1) ? zz[hw + 1].y - zz[hw].y : 0.f;
  } else if (h < NH - 1) {
    float a = (w < NW - 1) ? zz[hw + 1].y - zz[hw].y : 0.f;
    float bb = (w < NW - 1) ? zz[hw - NW + 1].y - zz[hw - NW].y : 0.f;
    divy = a - bb;
  } else {
    divy = -((w < NW - 1) ? zz[hw - NW + 1].y - zz[hw - NW].y : 0.f);
  }
  return divx + divy;
}

// b-term: div_x((u-v)_ch0) + div_y((u-v)_ch1)   (u, v planar 4-channel real)
DEVFN float divUV(const float* __restrict__ u, const float* __restrict__ v, int b, int h, int w) {
  const float* u0 = u + (b * 4 + 0) * NHW; const float* v0 = v + (b * 4 + 0) * NHW;
  const float* u1 = u + (b * 4 + 1) * NHW; const float* v1 = v + (b * 4 + 1) * NHW;
  int hw = h * NW + w;
  float divx, divy;
  if (w == 0)          divx = u0[hw] - v0[hw];
  else if (w < NW - 1) divx = (u0[hw] - v0[hw]) - (u0[hw - 1] - v0[hw - 1]);
  else                 divx = -(u0[hw - 1] - v0[hw - 1]);
  if (h == 0)          divy = u1[hw] - v1[hw];
  else if (h < NH - 1) divy = (u1[hw] - v1[hw]) - (u1[hw - NW] - v1[hw - NW]);
  else                 divy = -(u1[hw - NW] - v1[hw - NW]);
  return divx + divy;
}

DEVFN double shflxd(double v, int m) {
  union { double d; int i[2]; } a; a.d = v;
  a.i[0] = __shfl_xor(a.i[0], m, 64);
  a.i[1] = __shfl_xor(a.i[1], m, 64);
  return a.d;
}
DEVFN double waveRed(double v) {
#pragma unroll
  for (int m = 32; m; m >>= 1) v += shflxd(v, m);
  return v;
}

// reduce 1280 per-block partials -> scalar, broadcast (deterministic fixed order)
__device__ double redParts(const double* __restrict__ part, double* sdot, int t) {
  double v = part[t] + part[t + 320] + part[t + 640] + part[t + 960];
  v = waveRed(v);
  if ((t & 63) == 0) sdot[t >> 6] = v;
  __syncthreads();
  double s = sdot[0] + sdot[1] + sdot[2] + sdot[3] + sdot[4];
  __syncthreads();
  return s;
}

// reduce packed triple partials part3[blk*3+{0,1,2}] -> 3 scalars, broadcast
__device__ void redParts3(const double* __restrict__ part3, double* sdot, int t,
                          double& o0, double& o1, double& o2) {
  double s0 = 0, s1 = 0, s2 = 0;
#pragma unroll
  for (int j = 0; j < 4; j++) {
    int blk = t + j * 320;
    s0 += part3[blk * 3 + 0];
    s1 += part3[blk * 3 + 1];
    s2 += part3[blk * 3 + 2];
  }
  s0 = waveRed(s0); s1 = waveRed(s1); s2 = waveRed(s2);
  int wv = t >> 6;
  if ((t & 63) == 0) { sdot[wv * 3] = s0; sdot[wv * 3 + 1] = s1; sdot[wv * 3 + 2] = s2; }
  __syncthreads();
  double a0 = 0, a1 = 0, a2 = 0;
#pragma unroll
  for (int w2 = 0; w2 < 5; w2++) { a0 += sdot[w2 * 3]; a1 += sdot[w2 * 3 + 1]; a2 += sdot[w2 * 3 + 2]; }
  __syncthreads();
  o0 = a0; o1 = a1; o2 = a2;
}

__device__ void blockDot1(double a, double* sdot, int t, double* outp) {
  a = waveRed(a);
  if ((t & 63) == 0) sdot[t >> 6] = a;
  __syncthreads();
  if (t == 0) *outp = sdot[0] + sdot[1] + sdot[2] + sdot[3] + sdot[4];
  __syncthreads();
}

// packed write: o3[bid*3 + {0,1,2}]
__device__ void blockDot3p(double a, double b, double c, double* sdot, int t,
                           double* o3, int bid) {
  a = waveRed(a); b = waveRed(b); c = waveRed(c);
  int wv = t >> 6;
  if ((t & 63) == 0) { sdot[wv * 3] = a; sdot[wv * 3 + 1] = b; sdot[wv * 3 + 2] = c; }
  __syncthreads();
  if (t == 0) {
    double s0 = 0, s1 = 0, s2 = 0;
#pragma unroll
    for (int w2 = 0; w2 < 5; w2++) { s0 += sdot[w2 * 3]; s1 += sdot[w2 * 3 + 1]; s2 += sdot[w2 * 3 + 2]; }
    o3[bid * 3 + 0] = s0; o3[bid * 3 + 1] = s1; o3[bid * 3 + 2] = s2;
  }
  __syncthreads();
}

#define FFTK_SHARED                                     \
  __shared__ float2 sA[320];                            \
  __shared__ float2 sB[320];                            \
  __shared__ float2 sS[640];                            \
  __shared__ float2 stw[320];                           \
  __shared__ double sdot[16];                           \
  (void)sdot;                                           \
  const int t = threadIdx.x;                            \
  const int bid = blockIdx.x;                           \
  stw[t] = twg[t];

// Handoff rule (double-buffered transpose): every FFT kernel READS its line
// contiguously from one buffer at [gb*NHW + gl*NW + t] and WRITES the OTHER
// buffer transposed at [gb*NHW + o*NW + gl] (o = thread's output element,
// stored straight from registers). No dispatch reads and writes the same
// buffer -> no inter-block race; strided writes merge in-XCD via the swizzle.

// ---------------- kernels (grid = 1280 x 320 everywhere) ----------------

// twiddle table + transposed shifted/scaled mask misT[b][w][h]
__global__ __launch_bounds__(NTHR) void k_init(const float* __restrict__ mask,
                                               float* __restrict__ misT, float2* __restrict__ tw) {
  int t = threadIdx.x, bid = blockIdx.x;
  if (bid == 0) {
    double ang = -2.0 * 3.14159265358979323846 * (double)t / 320.0;
    tw[t] = make_float2((float)cos(ang), (float)sin(ang));
  }
  int i = bid * NTHR + t;  // exactly NB*NHW
  int b = i / NHW, hw = i % NHW, h = hw / NW, w = hw % NW;
  int hs = (h + 160) % 320, ws = (w + 160) % 320;
  misT[b * NHW + w * NW + h] = mask[b * NHW + hs * NW + ws] * (1.0f / 102400.0f);
}

// rows S*IFFT*S of y -> tA(T) and of mask*y -> tB(T) (y planar input). Swizzled.
__global__ __launch_bounds__(NTHR) void k0a(const float* __restrict__ y, const float* __restrict__ mask,
                                            float2* __restrict__ tA, float2* __restrict__ tB,
                                            const float2* __restrict__ twg) {
  FFTK_SHARED
  const int wid = swzcol(bid);
  const int gb = wid / NH, gl = wid % NH;
  const int rowBase = gb * NC2 + gl * NW;
  float sgn = (t & 1) ? -1.f : 1.f;
  sA[t] = make_float2(sgn * y[rowBase + t], sgn * y[rowBase + NHW + t]);
  __syncthreads();
  C2 a1 = fftp_core<1, false>(sA, sS, stw, t, nullptr);
  const int o = oidx(t);
  const float sgo = (o & 1) ? -1.f : 1.f;
  tA[gb * NHW + o * NW + gl] = make_float2(sgo * a1.x, sgo * a1.y);
  __syncthreads();  // all radix-5 reads of sA done before restaging
  float m = mask[gb * NHW + gl * NW + t];
  sA[t] = make_float2(sgn * m * y[rowBase + t], sgn * m * y[rowBase + NHW + t]);
  __syncthreads();
  C2 a2 = fftp_core<1, false>(sA, sS, stw, t, nullptr);
  tB[gb * NHW + o * NW + gl] = make_float2(sgo * a2.x, sgo * a2.y);
}

// cols S*IFFT*S (scale 1/320): tA -> x2, tB -> bdata2 (interleaved spatial). Swizzled.
__global__ __launch_bounds__(NTHR) void k0b(const float2* __restrict__ tA, const float2* __restrict__ tB,
                                            float2* __restrict__ x2, float2* __restrict__ bdata2,
                                            const float2* __restrict__ twg) {
  FFTK_SHARED
  const int wid = swzcol(bid);
  const int gb = wid / NH, gl = wid % NH;
  float sgn = (t & 1) ? -1.f : 1.f;
  {
    float2 v = tA[gb * NHW + gl * NW + t];
    sA[t] = make_float2(sgn * v.x, sgn * v.y);
  }
  __syncthreads();
  C2 a1 = fftp_core<1, false>(sA, sS, stw, t, nullptr);
  const int o = oidx(t);
  const float so = ((o & 1) ? -1.f : 1.f) * (1.f / 320.f);
  x2[gb * NHW + o * NW + gl] = make_float2(a1.x * so, a1.y * so);
  __syncthreads();  // all radix-5 reads of sA done before restaging
  {
    float2 v = tB[gb * NHW + gl * NW + t];
    sA[t] = make_float2(sgn * v.x, sgn * v.y);
  }
  __syncthreads();
  C2 a2 = fftp_core<1, false>(sA, sS, stw, t, nullptr);
  bdata2[gb * NHW + o * NW + gl] = make_float2(a2.x * so, a2.y * so);
}

// u = gradient(x), v = 0 (1 site/thread, raw bid); xc = x; rowFFT(x) -> tA(T). Swizzled FFT.
__global__ __launch_bounds__(NTHR) void ka0(const float2* __restrict__ x2, float2* __restrict__ xc2,
                                            float* __restrict__ u, float* __restrict__ v,
                                            float2* __restrict__ tA, const float2* __restrict__ twg) {
  FFTK_SHARED
  const int wid = swzcol(bid);
  const int gb = wid / NH, gl = wid % NH;
  {
    int i = bid * NTHR + t;
    int b = i / NHW, hw = i % NHW, h = hw / NW, w = hw % NW;
    const float2* zz = x2 + b * NHW;
    float2 z0 = zz[hw];
    float g0 = 0, g1 = 0, g2 = 0, g3 = 0;
    if (w < NW - 1) { float2 zr = zz[hw + 1]; g0 = zr.x - z0.x; g1 = zr.y - z0.y; }
    if (h < NH - 1) { float2 zd = zz[hw + NW]; g2 = zd.x - z0.x; g3 = zd.y - z0.y; }
    int b4 = b * 4 * NHW;
    u[b4 + hw] = g0;           v[b4 + hw] = 0.f;
    u[b4 + NHW + hw] = g1;     v[b4 + NHW + hw] = 0.f;
    u[b4 + 2 * NHW + hw] = g2; v[b4 + 2 * NHW + hw] = 0.f;
    u[b4 + 3 * NHW + hw] = g3; v[b4 + 3 * NHW + hw] = 0.f;
  }
  int idx = gb * NHW + gl * NW + t;
  float2 xv = x2[idx];
  xc2[idx] = xv;
  sA[t] = xv;
  __syncthreads();
  C2 a = fftp_core<-1, false>(sA, sS, stw, t, nullptr);
  tA[gb * NHW + oidx(t) * NW + gl] = make_float2(a.x, a.y);
}

// [it>0: reduce prev pres/dres -> hist; guarded u/v commit] ; colFM: tA -> tB. Swizzled.
__global__ __launch_bounds__(NTHR) void kb(const float2* __restrict__ tA, float2* __restrict__ tB,
                                           const float* __restrict__ misT,
                                           const float* __restrict__ un, const float* __restrict__ vn,
                                           float* __restrict__ u, float* __restrict__ v,
                                           const double* __restrict__ pPaPrev, const double* __restrict__ pPbPrev,
                                           double* __restrict__ hist_pres, double* __restrict__ hist_dres,
                                           const float2* __restrict__ twg, int it) {
  FFTK_SHARED
  const int wid = swzcol(bid);
  const int gb = wid / NH, gl = wid % NH;
  if (it > 0) {
    double ppa = redParts(pPaPrev, sdot, t);
    double ppb = redParts(pPbPrev, sdot, t);
    if (bid == 0 && t == 0) { hist_pres[it - 1] = ppa; hist_dres[it - 1] = ppb; }
    // commit guard is done_before(it-1) = OR_{j<=it-2} stop_j
    bool doneA = false;
    for (int j = 0; j <= it - 2; j++) {
      float pr = sqrtf((float)hist_pres[j]), dr = sqrtf((float)hist_dres[j]);
      doneA |= (pr < 1e-4f && dr < 1e-4f);
    }
    if (!doneA) {
      for (int i = wid * NTHR + t; i < NB * 4 * NHW; i += GRID * NTHR) { u[i] = un[i]; v[i] = vn[i]; }
    }
  }
  sA[t] = tA[gb * NHW + gl * NW + t];
  __syncthreads();
  C2 a1 = fftp_core<-1, true>(sA, sS, stw, t, misT + gb * NHW + gl * NW);
  const int o = oidx(t);
  sB[o] = make_float2(a1.x, a1.y);   // natural-order scatter feeds next fftp
  __syncthreads();
  C2 a2 = fftp_core<1, false>(sB, sS, stw, t, nullptr);
  tB[gb * NHW + o * NW + gl] = make_float2(a2.x, a2.y);
}

// rowIFFT(tB) -> A(x); r = p = (bdata + divUV) - A(x); rsold partials; rowFFT(p) -> tA(T). Swizzled.
__global__ __launch_bounds__(NTHR) void kcd(const float2* __restrict__ tB, float2* __restrict__ tA,
                                            const float2* __restrict__ x2,
                                            const float* __restrict__ u, const float* __restrict__ v,
                                            const float2* __restrict__ bdata2, float2* __restrict__ r2,
                                            float2* __restrict__ p2, double* __restrict__ pRS,
                                            const float2* __restrict__ twg) {
  FFTK_SHARED
  const int wid = swzcol(bid);
  const int gb = wid / NH, gl = wid % NH;
  sA[t] = tB[gb * NHW + gl * NW + t];
  __syncthreads();
  C2 a1 = fftp_core<1, false>(sA, sS, stw, t, nullptr);
  const int o = oidx(t);
  const int idxO = gb * NHW + gl * NW + o;
  float G = Gfunc2(x2, gb, gl, o);
  float d = divUV(u, v, gb, gl, o);
  float2 bd = bdata2[idxO];
  float rr = (bd.x + d) - (a1.x - G);
  float ri = (bd.y + d) - (a1.y - G);
  float2 rv = make_float2(rr, ri);
  r2[idxO] = rv; p2[idxO] = rv;
  double acc = (double)rr * rr + (double)ri * ri;
  blockDot1(acc, sdot, t, &pRS[bid]);   // internal syncs: sA reads complete
  sA[o] = rv;                           // natural-order restage of p
  __syncthreads();
  C2 a2 = fftp_core<-1, false>(sA, sS, stw, t, nullptr);
  tA[gb * NHW + o * NW + gl] = make_float2(a2.x, a2.y);
}

// k>=1: reduce dots (packed); update xc, r, p; rowFFT(p) -> tA(T). Swizzled.
__global__ __launch_bounds__(NTHR) void kd(float2* __restrict__ xc2, float2* __restrict__ r2,
                                           float2* __restrict__ p2, const float2* __restrict__ Ap2,
                                           float2* __restrict__ tA, const double* __restrict__ pRS,
                                           const double* __restrict__ pD3, double* __restrict__ hist_rs,
                                           const float2* __restrict__ twg, int k) {
  FFTK_SHARED
  const int wid = swzcol(bid);
  const int gb = wid / NH, gl = wid % NH;
  const int idx = gb * NHW + gl * NW + t;
  double pAp, rAp, A2;
  redParts3(pD3, sdot, t, pAp, rAp, A2);
  double rsold = (k == 1) ? redParts(pRS, sdot, t) : hist_rs[k - 2];
  float alpha = (float)rsold / ((float)pAp + 1e-12f);
  // exact algebraic expansion of ||r - alpha*Ap||^2 (no conjugacy assumption)
  double rsnew = rsold - 2.0 * (double)alpha * rAp + (double)alpha * (double)alpha * A2;
  if (bid == 0 && t == 0) hist_rs[k - 1] = rsnew;
  bool doneIn = false;
  for (int j = 0; j <= k - 2; j++) doneIn |= ((float)hist_rs[j] < 1e-10f);
  bool stop = ((float)rsnew < 1e-10f);
  bool doneP = doneIn || stop;
  float beta = (float)rsnew / (float)rsold;
  float2 pv = p2[idx], rv = r2[idx], av = Ap2[idx], xv = xc2[idx];
  if (!doneIn) {
    xv.x += alpha * pv.x; xv.y += alpha * pv.y;
    rv.x -= alpha * av.x; rv.y -= alpha * av.y;
  }
  float2 pn = doneP ? pv : make_float2(rv.x + beta * pv.x, rv.y + beta * pv.y);
  xc2[idx] = xv; r2[idx] = rv; p2[idx] = pn;
  sA[t] = pn;
  __syncthreads();
  C2 a = fftp_core<-1, false>(sA, sS, stw, t, nullptr);
  tA[gb * NHW + oidx(t) * NW + gl] = make_float2(a.x, a.y);
}

// plain colFM (mask fused into forward FFT tail): tA -> tB. Swizzled.
__global__ __launch_bounds__(NTHR) void ke(const float2* __restrict__ tA, float2* __restrict__ tB,
                                           const float* __restrict__ misT,
                                           const float2* __restrict__ twg) {
  FFTK_SHARED
  const int wid = swzcol(bid);
  const int gb = wid / NH, gl = wid % NH;
  sA[t] = tA[gb * NHW + gl * NW + t];
  __syncthreads();
  C2 a1 = fftp_core<-1, true>(sA, sS, stw, t, misT + gb * NHW + gl * NW);
  const int o = oidx(t);
  sB[o] = make_float2(a1.x, a1.y);   // natural-order scatter feeds next fftp
  __syncthreads();
  C2 a2 = fftp_core<1, false>(sB, sS, stw, t, nullptr);
  tB[gb * NHW + o * NW + gl] = make_float2(a2.x, a2.y);
}

// rowIFFT(tB) -> Ap = M(p) - G(p); packed dots p.Ap, r.Ap, Ap.Ap. Swizzled.
__global__ __launch_bounds__(NTHR) void kf(const float2* __restrict__ tB, const float2* __restrict__ p2,
                                           const float2* __restrict__ r2, float2* __restrict__ Ap2,
                                           double* __restrict__ pD3, const float2* __restrict__ twg) {
  FFTK_SHARED
  const int wid = swzcol(bid);
  const int gb = wid / NH, gl = wid % NH;
  sA[t] = tB[gb * NHW + gl * NW + t];
  __syncthreads();
  C2 a = fftp_core<1, false>(sA, sS, stw, t, nullptr);
  const int o = oidx(t);
  const int idxO = gb * NHW + gl * NW + o;
  float G = Gfunc2(p2, gb, gl, o);
  float Ar = a.x - G, Ai = a.y - G;
  Ap2[idxO] = make_float2(Ar, Ai);
  float2 pv = p2[idxO], rv = r2[idxO];
  double aP = (double)pv.x * Ar + (double)pv.y * Ai;
  double aR = (double)rv.x * Ar + (double)rv.y * Ai;
  double aA = (double)Ar * Ar + (double)Ai * Ai;
  blockDot3p(aP, aR, aA, sdot, t, pD3, bid);
}

// final CG x-update; xn -> tB (spatial); un/vn; pres partials. 1 site/thread.
__global__ __launch_bounds__(NTHR) void kh1(const float2* __restrict__ xc2, const float2* __restrict__ p2,
                                            const float* __restrict__ v, float2* __restrict__ tB,
                                            float* __restrict__ un, float* __restrict__ vn,
                                            const double* __restrict__ pD3, const double* __restrict__ hist_rs,
                                            double* __restrict__ pPaCur) {
  __shared__ double sdot[16];
  const int t = threadIdx.x, bid = blockIdx.x;
  double pAp, rApU, A2U;
  redParts3(pD3, sdot, t, pAp, rApU, A2U);
  (void)rApU; (void)A2U;
  double rsold = hist_rs[8];
  float alphaF = (float)rsold / ((float)pAp + 1e-12f);
  bool doneX = false;
  for (int j = 0; j <= 8; j++) doneX |= ((float)hist_rs[j] < 1e-10f);
  int i = bid * NTHR + t;
  int b = i / NHW, hw = i % NHW, h = hw / NW, w = hw % NW;
  int base2 = b * NHW;
  auto XN = [&](int off) {
    float2 vv = xc2[base2 + off];
    if (!doneX) {
      float2 pp = p2[base2 + off];
      vv.x += alphaF * pp.x; vv.y += alphaF * pp.y;
    }
    return vv;
  };
  float2 x0 = XN(hw);
  float g0 = 0, g1 = 0, g2 = 0, g3 = 0;
  if (w < NW - 1) { float2 xr = XN(hw + 1); g0 = xr.x - x0.x; g1 = xr.y - x0.y; }
  if (h < NH - 1) { float2 xd = XN(hw + NW); g2 = xd.x - x0.x; g3 = xd.y - x0.y; }
  tB[base2 + hw] = x0;
  float gs[4] = {g0, g1, g2, g3};
  double acc = 0.0;
#pragma unroll
  for (int ch = 0; ch < 4; ch++) {
    int ui = (b * 4 + ch) * NHW + hw;
    float vv = v[ui];
    float sv = gs[ch] + vv;
    float a2 = fabsf(sv) - THRESHc;
    float uo = (a2 > 0.f) ? copysignf(a2, sv) : 0.f;
    un[ui] = uo;
    vn[ui] = vv + gs[ch] - uo;
    float dd = gs[ch] - uo;
    acc += (double)dd * dd;
  }
  blockDot1(acc, sdot, t, &pPaCur[bid]);
}

// dres partials (raw bid); guarded x commit from tB(xn spatial); rowFFT(x) -> tA(T). Swizzled FFT.
__global__ __launch_bounds__(NTHR) void kh2a(float2* __restrict__ x2, float2* __restrict__ xc2,
                                             const float2* __restrict__ tB, float2* __restrict__ tA,
                                             const float* __restrict__ un,
                                             const float* __restrict__ u,
                                             const double* __restrict__ hist_pres,
                                             const double* __restrict__ hist_dres,
                                             double* __restrict__ pPbCur,
                                             const float2* __restrict__ twg, int it) {
  FFTK_SHARED
  const int wid = swzcol(bid);
  const int gb = wid / NH, gl = wid % NH;
  const int idx = gb * NHW + gl * NW + t;
  // done_before(it) = OR_{j<=it-1} stop_j  (hist[it-1] written by kb(it) this iter)
  bool doneA = false;
  for (int j = 0; j <= it - 1; j++) {
    float pr = sqrtf((float)hist_pres[j]), dr = sqrtf((float)hist_dres[j]);
    doneA |= (pr < 1e-4f && dr < 1e-4f);
  }
  {
    int i = bid * NTHR + t;
    int b = i / NHW, hw = i % NHW, h = hw / NW, w = hw % NW;
    const float* N0 = un + (b * 4 + 0) * NHW; const float* U0 = u + (b * 4 + 0) * NHW;
    const float* N1 = un + (b * 4 + 1) * NHW; const float* U1 = u + (b * 4 + 1) * NHW;
    float divx, divy;
    if (w == 0)          divx = N0[hw] - U0[hw];
    else if (w < NW - 1) divx = (N0[hw] - U0[hw]) - (N0[hw - 1] - U0[hw - 1]);
    else                 divx = -(N0[hw - 1] - U0[hw - 1]);
    if (h == 0)          divy = N1[hw] - U1[hw];
    else if (h < NH - 1) divy = (N1[hw] - U1[hw]) - (N1[hw - NW] - U1[hw - NW]);
    else                 divy = -(N1[hw - NW] - U1[hw - NW]);
    float d = divx + divy;
    double acc = (double)d * d;
    blockDot1(acc, sdot, t, &pPbCur[bid]);
  }
  float2 xn = tB[idx];
  float2 xf = doneA ? x2[idx] : xn;
  x2[idx] = xf; xc2[idx] = xf;
  sA[t] = xf;
  __syncthreads();
  C2 a = fftp_core<-1, false>(sA, sS, stw, t, nullptr);
  tA[gb * NHW + oidx(t) * NW + gl] = make_float2(a.x, a.y);
}

__global__ __launch_bounds__(NTHR) void k_out(const float2* __restrict__ x2,
                                              const double* __restrict__ hist_pres,
                                              const double* __restrict__ hist_dres,
                                              const double* __restrict__ pPa9,
                                              const double* __restrict__ pPb9,
                                              float* __restrict__ out) {
  __shared__ double sdot[16];
  const int t = threadIdx.x, bid = blockIdx.x;
  {
    int i = bid * NTHR + t;  // exactly NB*NHW sites
    int b = i / NHW, hw = i % NHW;
    float2 v = x2[b * NHW + hw];
    out[b * NC2 + hw] = v.x;
    out[b * NC2 + NHW + hw] = v.y;
  }
  if (bid == 0) {
    double p9 = redParts(pPa9, sdot, t);
    double d9 = redParts(pPb9, sdot, t);
    if (t == 0) {
      int count = 0; bool done = false; float presO = 0.f, dresO = 0.f;
      for (int it = 0; it < 10; ++it) {
        double hp = (it == 9) ? p9 : hist_pres[it];
        double hd = (it == 9) ? d9 : hist_dres[it];
        if (!done) {
          count++;
          presO = sqrtf((float)hp);
          dresO = sqrtf((float)hd);
          done = (presO < 1e-4f) && (dresO < 1e-4f);
        }
      }
      out[NB * NC2 + 0] = (float)count;
      out[NB * NC2 + 1] = presO;
      out[NB * NC2 + 2] = dresO;
    }
  }
}

}  // namespace

extern "C" void kernel_launch(void* const* d_in, const int* in_sizes, int n_in,
                              void* d_out, int out_size, void* d_ws, size_t ws_size,
                              hipStream_t stream) {
  (void)in_sizes; (void)n_in; (void)out_size; (void)ws_size;
  const float* y = (const float*)d_in[0];
  const float* mask = (const float*)d_in[1];
  float* out = (float*)d_out;
  float* wsf = (float*)d_ws;

  double* dws = (double*)wsf;
  double* pRS       = dws;           // 1280
  double* pD3       = dws + 1280;    // 3840 packed (pAp, rAp, ApAp per block)
  double* pPa       = dws + 5120;    // 2 x 1280 (parity)
  double* pPb       = dws + 7680;    // 2 x 1280 (parity)
  double* hist_rs   = dws + 10240;   // 16
  double* hist_pres = dws + 10256;   // 16
  double* hist_dres = dws + 10272;   // 16 -> ends at 10288 doubles

  float* fb = wsf + 20576;           // after 10288 doubles
  float2* tw = (float2*)fb; fb += 640;
  float* misT = fb; fb += (size_t)NB * NHW;
  float2* tA = (float2*)fb; fb += (size_t)2 * NB * NHW;
  float2* tB = (float2*)fb; fb += (size_t)2 * NB * NHW;
  auto take2 = [&](size_t n) { float2* ptr = (float2*)fb; fb += 2 * n; return ptr; };
  float2* x2     = take2((size_t)NB * NHW);
  float2* xc2    = take2((size_t)NB * NHW);
  float2* r2     = take2((size_t)NB * NHW);
  float2* p2     = take2((size_t)NB * NHW);
  float2* Ap2    = take2((size_t)NB * NHW);
  float2* bdata2 = take2((size_t)NB * NHW);
  auto take = [&](size_t n) { float* ptr = fb; fb += n; return ptr; };
  float* u  = take((size_t)NB * 4 * NHW);
  float* v  = take((size_t)NB * 4 * NHW);
  float* un = take((size_t)NB * 4 * NHW);
  float* vn = take((size_t)NB * 4 * NHW);

  k_init<<<GRID, NTHR, 0, stream>>>(mask, misT, tw);
  k0a<<<GRID, NTHR, 0, stream>>>(y, mask, tA, tB, tw);
  k0b<<<GRID, NTHR, 0, stream>>>(tA, tB, x2, bdata2, tw);
  ka0<<<GRID, NTHR, 0, stream>>>(x2, xc2, u, v, tA, tw);

  for (int it = 0; it < 10; ++it) {
    int prevPar = (it + 1) & 1;  // (it-1)&1
    int curPar = it & 1;
    kb<<<GRID, NTHR, 0, stream>>>(tA, tB, misT, un, vn, u, v,
                                  pPa + prevPar * 1280, pPb + prevPar * 1280,
                                  hist_pres, hist_dres, tw, it);
    kcd<<<GRID, NTHR, 0, stream>>>(tB, tA, x2, u, v, bdata2, r2, p2, pRS, tw);
    ke<<<GRID, NTHR, 0, stream>>>(tA, tB, misT, tw);
    kf<<<GRID, NTHR, 0, stream>>>(tB, p2, r2, Ap2, pD3, tw);
    for (int k = 1; k < 10; ++k) {
      kd<<<GRID, NTHR, 0, stream>>>(xc2, r2, p2, Ap2, tA, pRS, pD3, hist_rs, tw, k);
      ke<<<GRID, NTHR, 0, stream>>>(tA, tB, misT, tw);
      kf<<<GRID, NTHR, 0, stream>>>(tB, p2, r2, Ap2, pD3, tw);
    }
    kh1<<<GRID, NTHR, 0, stream>>>(xc2, p2, v, tB, un, vn, pD3, hist_rs, pPa + curPar * 1280);
    kh2a<<<GRID, NTHR, 0, stream>>>(x2, xc2, tB, tA, un, u, hist_pres, hist_dres,
                                    pPb + curPar * 1280, tw, it);
  }
  k_out<<<GRID, NTHR, 0, stream>>>(x2, hist_pres, hist_dres, pPa + 1280, pPb + 1280, out);
}